// Round 6
// baseline (686.982 us; speedup 1.0000x reference)
//
#include <hip/hip_runtime.h>

// MetaLayer GNN on MI355X — round 7: edge occupancy + fused node gather.
// (a) edge: __launch_bounds__(256,6) — VGPR=64 fits the ~85 cap, LDS allows 7
//     blocks/CU, so 6 blocks/CU instead of 4 (occ 40 -> ~58%). ET 5 -> 10
//     halves per-block weight-fragment reload.
// (b) node: the two CSR gather streams were SEQUENTIAL dependency chains
//     ((g1+g2) x ~500cy L3 latency, degree-divergence inflated). Fused into
//     one fully-predicated loop: all 18 loads per iteration issue
//     unconditionally (eid clamped to 0 past degree — broadcast L1 hit),
//     adds are per-lane masked. Serial depth -> max(g1,g2), chains overlap.
//     NT2 2 -> 4 amortizes weight loads.

constexpr int NA = 100000;
constexpr int NEDGE = 400000;
constexpr int DN = 64;
constexpr int DE = 32;
constexpr int DH = 64;
constexpr int CAP = 32;                   // bucket capacity (max degree)

constexpr int ET = 10;                    // edge tiles per block (64 edges each)
constexpr int NT2 = 4;                    // node tiles per block

constexpr int FSTR = 168;  // edge concat-feature stride (160 + 8 pad)
constexpr int NSTR = 136;  // node concat-feature stride (128 + 8 pad)
constexpr int HSTR = 72;   // hidden stride (64 + 8 pad)

typedef __bf16 bf16x8 __attribute__((ext_vector_type(8)));
typedef __bf16 bf16x4 __attribute__((ext_vector_type(4)));
typedef float f32x4 __attribute__((ext_vector_type(4)));
typedef int   i32x4 __attribute__((ext_vector_type(4)));

// ---------------- prep: x -> bf16 copy + zero counters ----------------
__global__ __launch_bounds__(256) void prep_kernel(
    const float4* __restrict__ xa, const float4* __restrict__ xb,
    __bf16* __restrict__ xab, int* __restrict__ cnt)
{
    int i = blockIdx.x * 256 + threadIdx.x;
    int stride = gridDim.x * 256;
    constexpr int N4 = NA * DN / 4;       // 1.6M float4 per input
    for (int j = i; j < N4; j += stride) {
        float4 v = xa[j];
        bf16x4 t = {(__bf16)v.x, (__bf16)v.y, (__bf16)v.z, (__bf16)v.w};
        *(bf16x4*)&xab[(size_t)j * 4] = t;
    }
    for (int j = i; j < N4; j += stride) {
        float4 v = xb[j];
        bf16x4 t = {(__bf16)v.x, (__bf16)v.y, (__bf16)v.z, (__bf16)v.w};
        *(bf16x4*)&xab[(size_t)NA * DN + (size_t)j * 4] = t;
    }
    for (int j = i; j < 4 * NA; j += stride) cnt[j] = 0;
}

// ---------------- edge kernel ----------------
__global__ __launch_bounds__(256, 6) void edge_kernel(
    const __bf16* __restrict__ xab,   // [2*NA][64] bf16 (a rows then b rows)
    const int* __restrict__ ei_aa, const int* __restrict__ ei_ab, const int* __restrict__ ei_bb,
    const float* __restrict__ ea_aa, const float* __restrict__ ea_ab, const float* __restrict__ ea_bb,
    const float* __restrict__ We1, const float* __restrict__ be1,
    const float* __restrict__ We2, const float* __restrict__ be2,
    float* __restrict__ ne_out,   // 3 ne arrays back-to-back, [3*NEDGE][32]
    int* __restrict__ wsi)        // lists[4*NA*CAP] ++ cnt[4*NA]
{
    __shared__ __bf16 feat[64 * FSTR];   // concat features, [64 edges][160]

    const int tid = threadIdx.x;
    constexpr int BPT = NEDGE / (64 * ET);   // 625 blocks per edge type
    const int k   = blockIdx.x / BPT;        // edge type (block-uniform)
    const int blk = blockIdx.x % BPT;
    const int eb  = blk * (64 * ET);         // first edge of this block

    const int*   ei = (k == 0) ? ei_aa : (k == 1) ? ei_ab : ei_bb;
    const float* ea = (k == 0) ? ea_aa : (k == 1) ? ea_ab : ea_bb;
    const __bf16* x1 = xab + ((k == 2) ? (size_t)NA * DN : 0);
    const __bf16* x2 = xab + ((k == 0) ? 0 : (size_t)NA * DN);
    const float* __restrict__ W1 = We1 + (size_t)k * (2 * DN + DE) * DH;
    const float* __restrict__ W2 = We2 + (size_t)k * DH * DE;

    const int w = tid >> 6, lane = tid & 63;
    const int m16 = lane & 15, quad = lane >> 4;
    const int q = tid & 3, el = tid >> 2;

    int* lists = wsi;
    int* cnt   = wsi + (size_t)4 * NA * CAP;

    // ---- weights + biases: once per block (amortized over ET tiles) ----
    bf16x8 b1f[5];
    {
        const float* wp = W1 + (size_t)(quad * 8) * DH + (w * 16 + m16);
#pragma unroll
        for (int kk = 0; kk < 5; kk++)
#pragma unroll
            for (int j = 0; j < 8; j++)
                b1f[kk][j] = (__bf16)wp[(kk * 32 + j) * DH];
    }
    bf16x8 b2f[2][2];
    {
        const float* wp = W2 + (size_t)(quad * 8) * DE + m16;
#pragma unroll
        for (int nt = 0; nt < 2; nt++)
#pragma unroll
            for (int kk = 0; kk < 2; kk++)
#pragma unroll
                for (int j = 0; j < 8; j++)
                    b2f[nt][kk][j] = (__bf16)wp[(kk * 32 + j) * DE + nt * 16];
    }
    const float b1c  = be1[k * DH + w * 16 + m16];
    const float b2c0 = be2[k * DE + m16];
    const float b2c1 = be2[k * DE + 16 + m16];

    // ---- prefetch state (rolling, depth 2 on ei, depth 1 on x/ea) ----
    int src, dst, src_n, dst_n;
    bf16x8 ra0, ra1, rb0, rb1;
    float4 re0, re1;
    {
        const int e0 = eb + el;
        src = ei[e0]; dst = ei[NEDGE + e0];
        const bf16x8* p1 = (const bf16x8*)(x1 + (size_t)src * DN + q * 16);
        const bf16x8* p2 = (const bf16x8*)(x2 + (size_t)dst * DN + q * 16);
        const float4* pe = (const float4*)(ea + (size_t)e0 * DE);
        ra0 = p1[0]; ra1 = p1[1]; rb0 = p2[0]; rb1 = p2[1];
        re0 = pe[q * 2]; re1 = pe[q * 2 + 1];
        const int e1 = eb + 64 + el;
        src_n = ei[e1]; dst_n = ei[NEDGE + e1];
    }

#pragma unroll 1
    for (int t = 0; t < ET; t++) {
        // ---- stage current tile (prefetched regs -> LDS) + CSR publish ----
        *(bf16x8*)&feat[el * FSTR + q * 16]          = ra0;
        *(bf16x8*)&feat[el * FSTR + q * 16 + 8]      = ra1;
        *(bf16x8*)&feat[el * FSTR + 64 + q * 16]     = rb0;
        *(bf16x8*)&feat[el * FSTR + 64 + q * 16 + 8] = rb1;
        {
            bf16x4 t0 = {(__bf16)re0.x, (__bf16)re0.y, (__bf16)re0.z, (__bf16)re0.w};
            bf16x4 t1 = {(__bf16)re1.x, (__bf16)re1.y, (__bf16)re1.z, (__bf16)re1.w};
            *(bf16x4*)&feat[el * FSTR + 128 + q * 8]     = t0;
            *(bf16x4*)&feat[el * FSTR + 128 + q * 8 + 4] = t1;
        }
        if (q == 0) {
            const int e = eb + t * 64 + el;
            if (k == 0) {
                int p = atomicAdd(&cnt[src], 1);
                if (p < CAP) lists[(size_t)src * CAP + p] = e;
            } else if (k == 1) {
                int p = atomicAdd(&cnt[NA + src], 1);
                if (p < CAP) lists[((size_t)NA + src) * CAP + p] = e;
                int p2 = atomicAdd(&cnt[2 * NA + dst], 1);
                if (p2 < CAP) lists[((size_t)2 * NA + dst) * CAP + p2] = e;
            } else {
                int p = atomicAdd(&cnt[3 * NA + src], 1);
                if (p < CAP) lists[((size_t)3 * NA + src) * CAP + p] = e;
            }
        }
        // ---- issue next tile's loads (in flight across the MFMA phases) ----
        if (t + 1 < ET) {
            src = src_n; dst = dst_n;
            const int e1 = eb + (t + 1) * 64 + el;
            const bf16x8* p1 = (const bf16x8*)(x1 + (size_t)src * DN + q * 16);
            const bf16x8* p2 = (const bf16x8*)(x2 + (size_t)dst * DN + q * 16);
            const float4* pe = (const float4*)(ea + (size_t)e1 * DE);
            ra0 = p1[0]; ra1 = p1[1]; rb0 = p2[0]; rb1 = p2[1];
            re0 = pe[q * 2]; re1 = pe[q * 2 + 1];
            if (t + 2 < ET) {
                const int e2 = eb + (t + 2) * 64 + el;
                src_n = ei[e2]; dst_n = ei[NEDGE + e2];
            }
        }
        __syncthreads();

        // ---- layer 1: h[64][64] = feat @ W1 ; wave w owns cols 16w.. ----
        f32x4 acc0 = {0.f,0.f,0.f,0.f}, acc1 = acc0, acc2v = acc0, acc3 = acc0;
#pragma unroll
        for (int kk = 0; kk < 5; kk++) {
            bf16x8 a0 = *(const bf16x8*)&feat[( 0 + m16) * FSTR + kk * 32 + quad * 8];
            bf16x8 a1 = *(const bf16x8*)&feat[(16 + m16) * FSTR + kk * 32 + quad * 8];
            bf16x8 a2 = *(const bf16x8*)&feat[(32 + m16) * FSTR + kk * 32 + quad * 8];
            bf16x8 a3 = *(const bf16x8*)&feat[(48 + m16) * FSTR + kk * 32 + quad * 8];
            acc0 = __builtin_amdgcn_mfma_f32_16x16x32_bf16(a0, b1f[kk], acc0, 0, 0, 0);
            acc1 = __builtin_amdgcn_mfma_f32_16x16x32_bf16(a1, b1f[kk], acc1, 0, 0, 0);
            acc2v = __builtin_amdgcn_mfma_f32_16x16x32_bf16(a2, b1f[kk], acc2v, 0, 0, 0);
            acc3 = __builtin_amdgcn_mfma_f32_16x16x32_bf16(a3, b1f[kk], acc3, 0, 0, 0);
        }
        __syncthreads();                 // all feat reads done before aliasing
        __bf16* hbuf = feat;             // h [64 edges][64], stride HSTR
        {
            f32x4 av[4] = {acc0, acc1, acc2v, acc3};
#pragma unroll
            for (int mt = 0; mt < 4; mt++)
#pragma unroll
                for (int r = 0; r < 4; r++) {
                    float v = av[mt][r] + b1c;
                    v = fmaxf(v, 0.f);
                    hbuf[(mt * 16 + quad * 4 + r) * HSTR + w * 16 + m16] = (__bf16)v;
                }
        }
        __syncthreads();

        // ---- layer 2: o[64][32] = relu(h) @ W2 ----
        f32x4 o0 = {0.f,0.f,0.f,0.f}, o1 = o0;
#pragma unroll
        for (int kk = 0; kk < 2; kk++) {
            bf16x8 a = *(const bf16x8*)&hbuf[(w * 16 + m16) * HSTR + kk * 32 + quad * 8];
            o0 = __builtin_amdgcn_mfma_f32_16x16x32_bf16(a, b2f[0][kk], o0, 0, 0, 0);
            o1 = __builtin_amdgcn_mfma_f32_16x16x32_bf16(a, b2f[1][kk], o1, 0, 0, 0);
        }
        // ---- epilogue: write ne ----
        {
            const size_t row0 = (size_t)k * NEDGE + eb + t * 64;
#pragma unroll
            for (int r = 0; r < 4; r++) {
                const int er = w * 16 + quad * 4 + r;
                ne_out[(row0 + er) * DE + m16]      = o0[r] + b2c0;
                ne_out[(row0 + er) * DE + 16 + m16] = o1[r] + b2c1;
            }
        }
        __syncthreads();                 // h reads done -> next stage may write feat
    }
}

// ---------------- node kernel ----------------
__global__ __launch_bounds__(256, 4) void node_kernel(
    const float* __restrict__ x_a, const float* __restrict__ x_b,
    const float* __restrict__ Wn1, const float* __restrict__ bn1,
    const float* __restrict__ Wn2, const float* __restrict__ bn2,
    float* __restrict__ out,      // nx_a then nx_b, [2*NA][64]
    const float* __restrict__ ne, // [3*NEDGE][32]
    const int* __restrict__ wsi)  // lists ++ cnt
{
    __shared__ __bf16 feat[64 * NSTR];   // concat features [64 nodes][128]

    const int tid = threadIdx.x;
    constexpr int BPT = (NA + 64 * NT2 - 1) / (64 * NT2);  // 391
    const int typ = blockIdx.x / BPT;    // node type (block-uniform)
    const int blk = blockIdx.x % BPT;

    const float* x = typ ? x_b : x_a;
    const float* __restrict__ W1 = Wn1 + (size_t)typ * (DN + 2 * DE) * DH;
    const float* __restrict__ W2 = Wn2 + (size_t)typ * DH * DN;

    const int w = tid >> 6, lane = tid & 63;
    const int m16 = lane & 15, quad = lane >> 4;
    const int q = tid & 3, nl = tid >> 2;

    // ---- weights + biases: once per block ----
    bf16x8 b1f[4];
    {
        const float* wp = W1 + (size_t)(quad * 8) * DH + (w * 16 + m16);
#pragma unroll
        for (int kk = 0; kk < 4; kk++)
#pragma unroll
            for (int j = 0; j < 8; j++)
                b1f[kk][j] = (__bf16)wp[(kk * 32 + j) * DH];
    }
    bf16x8 b2f[4][2];
    {
        const float* wp = W2 + (size_t)(quad * 8) * DN + m16;
#pragma unroll
        for (int nt = 0; nt < 4; nt++)
#pragma unroll
            for (int kk = 0; kk < 2; kk++)
#pragma unroll
                for (int j = 0; j < 8; j++)
                    b2f[nt][kk][j] = (__bf16)wp[(kk * 32 + j) * DN + nt * 16];
    }
    const float b1c = bn1[typ * DH + w * 16 + m16];
    float b2c[4];
#pragma unroll
    for (int nt = 0; nt < 4; nt++) b2c[nt] = bn2[typ * DN + nt * 16 + m16];

    const int* lists = wsi;
    const int* cnt   = wsi + (size_t)4 * NA * CAP;

#pragma unroll 1
    for (int tt = 0; tt < NT2; tt++) {
        const int nb = (blk * NT2 + tt) * 64;
        if (nb >= NA) break;             // block-uniform

        // ---- gather: x | mean1 | mean2 — fused dual-stream predicated loop ----
        {
            const int n = nb + nl;
            const int ng = (n < NA) ? n : NA - 1;
            const int slot1 = (typ ? 2 * NA : 0) + ng;
            const int slot2 = (typ ? 3 * NA : NA) + ng;
            const float* neb1 = ne + (size_t)(typ ? 1 : 0) * NEDGE * DE + q * 8;
            const float* neb2 = ne + (size_t)(typ ? 2 : 1) * NEDGE * DE + q * 8;
            const int deg1 = min(cnt[slot1], CAP);
            const int deg2 = min(cnt[slot2], CAP);
            const int dmax = max(deg1, deg2);
            const int* L1 = lists + (size_t)slot1 * CAP;
            const int* L2 = lists + (size_t)slot2 * CAP;

            f32x4 s1a = {0.f,0.f,0.f,0.f}, s1b = s1a, s2a = s1a, s2b = s1a;
            for (int d = 0; d < dmax; d += 4) {
                // list slots 0..31 always allocated; entries past deg are
                // clamped to eid 0 (valid row, masked out of the sum).
                i32x4 e4a = *(const i32x4*)&L1[d];
                i32x4 e4b = *(const i32x4*)&L2[d];
#pragma unroll
                for (int i = 0; i < 4; i++) {
                    const bool ok1 = (d + i < deg1);
                    const bool ok2 = (d + i < deg2);
                    const int e1 = ok1 ? e4a[i] : 0;
                    const int e2 = ok2 ? e4b[i] : 0;
                    const f32x4* r1 = (const f32x4*)(neb1 + (size_t)e1 * DE);
                    const f32x4* r2 = (const f32x4*)(neb2 + (size_t)e2 * DE);
                    f32x4 u1 = r1[0], v1 = r1[1];
                    f32x4 u2 = r2[0], v2 = r2[1];
                    if (ok1) { s1a += u1; s1b += v1; }
                    if (ok2) { s2a += u2; s2b += v2; }
                }
            }
            const float inv1 = 1.0f / fmaxf((float)deg1, 1.0f);
            const float inv2 = 1.0f / fmaxf((float)deg2, 1.0f);
            s1a *= inv1; s1b *= inv1; s2a *= inv2; s2b *= inv2;

            const float4* px = (const float4*)(x + (size_t)ng * DN);
#pragma unroll
            for (int i = 0; i < 4; i++) {
                float4 v = px[q * 4 + i];
                bf16x4 t4 = {(__bf16)v.x, (__bf16)v.y, (__bf16)v.z, (__bf16)v.w};
                *(bf16x4*)&feat[nl * NSTR + q * 16 + i * 4] = t4;
            }
            bf16x4 m1a = {(__bf16)s1a[0], (__bf16)s1a[1], (__bf16)s1a[2], (__bf16)s1a[3]};
            bf16x4 m1b = {(__bf16)s1b[0], (__bf16)s1b[1], (__bf16)s1b[2], (__bf16)s1b[3]};
            bf16x4 m2a = {(__bf16)s2a[0], (__bf16)s2a[1], (__bf16)s2a[2], (__bf16)s2a[3]};
            bf16x4 m2b = {(__bf16)s2b[0], (__bf16)s2b[1], (__bf16)s2b[2], (__bf16)s2b[3]};
            *(bf16x4*)&feat[nl * NSTR + 64 + q * 8 + 0] = m1a;
            *(bf16x4*)&feat[nl * NSTR + 64 + q * 8 + 4] = m1b;
            *(bf16x4*)&feat[nl * NSTR + 96 + q * 8 + 0] = m2a;
            *(bf16x4*)&feat[nl * NSTR + 96 + q * 8 + 4] = m2b;
        }
        __syncthreads();

        // ---- layer 1: h = feat[64][128] @ Wn1 ----
        f32x4 acc0 = {0.f,0.f,0.f,0.f}, acc1 = acc0, acc2v = acc0, acc3 = acc0;
#pragma unroll
        for (int kk = 0; kk < 4; kk++) {
            bf16x8 a0 = *(const bf16x8*)&feat[( 0 + m16) * NSTR + kk * 32 + quad * 8];
            bf16x8 a1 = *(const bf16x8*)&feat[(16 + m16) * NSTR + kk * 32 + quad * 8];
            bf16x8 a2 = *(const bf16x8*)&feat[(32 + m16) * NSTR + kk * 32 + quad * 8];
            bf16x8 a3 = *(const bf16x8*)&feat[(48 + m16) * NSTR + kk * 32 + quad * 8];
            acc0 = __builtin_amdgcn_mfma_f32_16x16x32_bf16(a0, b1f[kk], acc0, 0, 0, 0);
            acc1 = __builtin_amdgcn_mfma_f32_16x16x32_bf16(a1, b1f[kk], acc1, 0, 0, 0);
            acc2v = __builtin_amdgcn_mfma_f32_16x16x32_bf16(a2, b1f[kk], acc2v, 0, 0, 0);
            acc3 = __builtin_amdgcn_mfma_f32_16x16x32_bf16(a3, b1f[kk], acc3, 0, 0, 0);
        }
        __syncthreads();
        __bf16* hbuf = feat;             // alias, h [64 nodes][64], stride HSTR
        {
            f32x4 av[4] = {acc0, acc1, acc2v, acc3};
#pragma unroll
            for (int mt = 0; mt < 4; mt++)
#pragma unroll
                for (int r = 0; r < 4; r++) {
                    float v = av[mt][r] + b1c;
                    v = fmaxf(v, 0.f);
                    hbuf[(mt * 16 + quad * 4 + r) * HSTR + w * 16 + m16] = (__bf16)v;
                }
        }
        __syncthreads();

        // ---- layer 2: nx[64][64] = relu(h) @ Wn2 ----
        f32x4 o0 = {0.f,0.f,0.f,0.f}, o1 = o0, o2 = o0, o3 = o0;
#pragma unroll
        for (int kk = 0; kk < 2; kk++) {
            bf16x8 a = *(const bf16x8*)&hbuf[(w * 16 + m16) * HSTR + kk * 32 + quad * 8];
            o0 = __builtin_amdgcn_mfma_f32_16x16x32_bf16(a, b2f[0][kk], o0, 0, 0, 0);
            o1 = __builtin_amdgcn_mfma_f32_16x16x32_bf16(a, b2f[1][kk], o1, 0, 0, 0);
            o2 = __builtin_amdgcn_mfma_f32_16x16x32_bf16(a, b2f[2][kk], o2, 0, 0, 0);
            o3 = __builtin_amdgcn_mfma_f32_16x16x32_bf16(a, b2f[3][kk], o3, 0, 0, 0);
        }
#pragma unroll
        for (int nt = 0; nt < 4; nt++) {
            const int col = nt * 16 + m16;
            const f32x4 oo = (nt == 0) ? o0 : (nt == 1) ? o1 : (nt == 2) ? o2 : o3;
#pragma unroll
            for (int r = 0; r < 4; r++) {
                const int n = nb + w * 16 + quad * 4 + r;
                if (n < NA)
                    out[((size_t)typ * NA + n) * DN + col] = oo[r] + b2c[nt];
            }
        }
        __syncthreads();                 // h reads done -> next tile stage
    }
}

extern "C" void kernel_launch(void* const* d_in, const int* in_sizes, int n_in,
                              void* d_out, int out_size, void* d_ws, size_t ws_size,
                              hipStream_t stream)
{
    const float* x_a  = (const float*)d_in[0];
    const float* x_b  = (const float*)d_in[1];
    const int*   ei_aa = (const int*)d_in[2];
    const int*   ei_ab = (const int*)d_in[3];
    const int*   ei_bb = (const int*)d_in[4];
    const float* ea_aa = (const float*)d_in[5];
    const float* ea_ab = (const float*)d_in[6];
    const float* ea_bb = (const float*)d_in[7];
    const float* We1 = (const float*)d_in[8];
    const float* be1 = (const float*)d_in[9];
    const float* We2 = (const float*)d_in[10];
    const float* be2 = (const float*)d_in[11];
    const float* Wn1 = (const float*)d_in[12];
    const float* bn1 = (const float*)d_in[13];
    const float* Wn2 = (const float*)d_in[14];
    const float* bn2 = (const float*)d_in[15];

    float* out = (float*)d_out;
    int*   wsi = (int*)d_ws;

    // bf16 x copy lives in out's nx region (25.6 MB < 51.2 MB); edge kernel
    // reads it, node kernel overwrites it with the final nx.
    __bf16* xab = (__bf16*)out;
    int* cnt = wsi + (size_t)4 * NA * CAP;

    prep_kernel<<<2048, 256, 0, stream>>>((const float4*)x_a, (const float4*)x_b,
                                          xab, cnt);

    constexpr int BPT_E = NEDGE / (64 * ET);     // 625
    edge_kernel<<<3 * BPT_E, 256, 0, stream>>>(
        xab, ei_aa, ei_ab, ei_bb, ea_aa, ea_ab, ea_bb,
        We1, be1, We2, be2, out + (size_t)2 * NA * DN, wsi);

    constexpr int BPT_N = (NA + 64 * NT2 - 1) / (64 * NT2);  // 391
    node_kernel<<<2 * BPT_N, 256, 0, stream>>>(
        x_a, x_b, Wn1, bn1, Wn2, bn2, out, out + (size_t)2 * NA * DN, wsi);
}

// Round 7
// 565.740 us; speedup vs baseline: 1.2143x; 1.2143x over previous
//
#include <hip/hip_runtime.h>

// MetaLayer GNN on MI355X — round 8: revert the spill.
// Round-7 counters: __launch_bounds__(256,6) cut the VGPR budget to ~85 <
// the kernel's ~100 natural usage -> prefetch state spilled to scratch
// (VGPR_Count 64->40, FETCH +243 MB, WRITE +121 MB, dur 192->317 µs).
// Revert edge to (256,4) (128-reg budget, known-good 64-VGPR codegen),
// KEEP ET=10 (weight amortization, register-neutral) and the round-7
// node-side fused predicated gather (measured ~neutral-to-positive).

constexpr int NA = 100000;
constexpr int NEDGE = 400000;
constexpr int DN = 64;
constexpr int DE = 32;
constexpr int DH = 64;
constexpr int CAP = 32;                   // bucket capacity (max degree)

constexpr int ET = 10;                    // edge tiles per block (64 edges each)
constexpr int NT2 = 4;                    // node tiles per block

constexpr int FSTR = 168;  // edge concat-feature stride (160 + 8 pad)
constexpr int NSTR = 136;  // node concat-feature stride (128 + 8 pad)
constexpr int HSTR = 72;   // hidden stride (64 + 8 pad)

typedef __bf16 bf16x8 __attribute__((ext_vector_type(8)));
typedef __bf16 bf16x4 __attribute__((ext_vector_type(4)));
typedef float f32x4 __attribute__((ext_vector_type(4)));
typedef int   i32x4 __attribute__((ext_vector_type(4)));

// ---------------- prep: x -> bf16 copy + zero counters ----------------
__global__ __launch_bounds__(256) void prep_kernel(
    const float4* __restrict__ xa, const float4* __restrict__ xb,
    __bf16* __restrict__ xab, int* __restrict__ cnt)
{
    int i = blockIdx.x * 256 + threadIdx.x;
    int stride = gridDim.x * 256;
    constexpr int N4 = NA * DN / 4;       // 1.6M float4 per input
    for (int j = i; j < N4; j += stride) {
        float4 v = xa[j];
        bf16x4 t = {(__bf16)v.x, (__bf16)v.y, (__bf16)v.z, (__bf16)v.w};
        *(bf16x4*)&xab[(size_t)j * 4] = t;
    }
    for (int j = i; j < N4; j += stride) {
        float4 v = xb[j];
        bf16x4 t = {(__bf16)v.x, (__bf16)v.y, (__bf16)v.z, (__bf16)v.w};
        *(bf16x4*)&xab[(size_t)NA * DN + (size_t)j * 4] = t;
    }
    for (int j = i; j < 4 * NA; j += stride) cnt[j] = 0;
}

// ---------------- edge kernel ----------------
__global__ __launch_bounds__(256, 4) void edge_kernel(
    const __bf16* __restrict__ xab,   // [2*NA][64] bf16 (a rows then b rows)
    const int* __restrict__ ei_aa, const int* __restrict__ ei_ab, const int* __restrict__ ei_bb,
    const float* __restrict__ ea_aa, const float* __restrict__ ea_ab, const float* __restrict__ ea_bb,
    const float* __restrict__ We1, const float* __restrict__ be1,
    const float* __restrict__ We2, const float* __restrict__ be2,
    float* __restrict__ ne_out,   // 3 ne arrays back-to-back, [3*NEDGE][32]
    int* __restrict__ wsi)        // lists[4*NA*CAP] ++ cnt[4*NA]
{
    __shared__ __bf16 feat[64 * FSTR];   // concat features, [64 edges][160]

    const int tid = threadIdx.x;
    constexpr int BPT = NEDGE / (64 * ET);   // 625 blocks per edge type
    const int k   = blockIdx.x / BPT;        // edge type (block-uniform)
    const int blk = blockIdx.x % BPT;
    const int eb  = blk * (64 * ET);         // first edge of this block

    const int*   ei = (k == 0) ? ei_aa : (k == 1) ? ei_ab : ei_bb;
    const float* ea = (k == 0) ? ea_aa : (k == 1) ? ea_ab : ea_bb;
    const __bf16* x1 = xab + ((k == 2) ? (size_t)NA * DN : 0);
    const __bf16* x2 = xab + ((k == 0) ? 0 : (size_t)NA * DN);
    const float* __restrict__ W1 = We1 + (size_t)k * (2 * DN + DE) * DH;
    const float* __restrict__ W2 = We2 + (size_t)k * DH * DE;

    const int w = tid >> 6, lane = tid & 63;
    const int m16 = lane & 15, quad = lane >> 4;
    const int q = tid & 3, el = tid >> 2;

    int* lists = wsi;
    int* cnt   = wsi + (size_t)4 * NA * CAP;

    // ---- weights + biases: once per block (amortized over ET tiles) ----
    bf16x8 b1f[5];
    {
        const float* wp = W1 + (size_t)(quad * 8) * DH + (w * 16 + m16);
#pragma unroll
        for (int kk = 0; kk < 5; kk++)
#pragma unroll
            for (int j = 0; j < 8; j++)
                b1f[kk][j] = (__bf16)wp[(kk * 32 + j) * DH];
    }
    bf16x8 b2f[2][2];
    {
        const float* wp = W2 + (size_t)(quad * 8) * DE + m16;
#pragma unroll
        for (int nt = 0; nt < 2; nt++)
#pragma unroll
            for (int kk = 0; kk < 2; kk++)
#pragma unroll
                for (int j = 0; j < 8; j++)
                    b2f[nt][kk][j] = (__bf16)wp[(kk * 32 + j) * DE + nt * 16];
    }
    const float b1c  = be1[k * DH + w * 16 + m16];
    const float b2c0 = be2[k * DE + m16];
    const float b2c1 = be2[k * DE + 16 + m16];

    // ---- prefetch state (rolling, depth 2 on ei, depth 1 on x/ea) ----
    int src, dst, src_n, dst_n;
    bf16x8 ra0, ra1, rb0, rb1;
    float4 re0, re1;
    {
        const int e0 = eb + el;
        src = ei[e0]; dst = ei[NEDGE + e0];
        const bf16x8* p1 = (const bf16x8*)(x1 + (size_t)src * DN + q * 16);
        const bf16x8* p2 = (const bf16x8*)(x2 + (size_t)dst * DN + q * 16);
        const float4* pe = (const float4*)(ea + (size_t)e0 * DE);
        ra0 = p1[0]; ra1 = p1[1]; rb0 = p2[0]; rb1 = p2[1];
        re0 = pe[q * 2]; re1 = pe[q * 2 + 1];
        const int e1 = eb + 64 + el;
        src_n = ei[e1]; dst_n = ei[NEDGE + e1];
    }

#pragma unroll 1
    for (int t = 0; t < ET; t++) {
        // ---- stage current tile (prefetched regs -> LDS) + CSR publish ----
        *(bf16x8*)&feat[el * FSTR + q * 16]          = ra0;
        *(bf16x8*)&feat[el * FSTR + q * 16 + 8]      = ra1;
        *(bf16x8*)&feat[el * FSTR + 64 + q * 16]     = rb0;
        *(bf16x8*)&feat[el * FSTR + 64 + q * 16 + 8] = rb1;
        {
            bf16x4 t0 = {(__bf16)re0.x, (__bf16)re0.y, (__bf16)re0.z, (__bf16)re0.w};
            bf16x4 t1 = {(__bf16)re1.x, (__bf16)re1.y, (__bf16)re1.z, (__bf16)re1.w};
            *(bf16x4*)&feat[el * FSTR + 128 + q * 8]     = t0;
            *(bf16x4*)&feat[el * FSTR + 128 + q * 8 + 4] = t1;
        }
        if (q == 0) {
            const int e = eb + t * 64 + el;
            if (k == 0) {
                int p = atomicAdd(&cnt[src], 1);
                if (p < CAP) lists[(size_t)src * CAP + p] = e;
            } else if (k == 1) {
                int p = atomicAdd(&cnt[NA + src], 1);
                if (p < CAP) lists[((size_t)NA + src) * CAP + p] = e;
                int p2 = atomicAdd(&cnt[2 * NA + dst], 1);
                if (p2 < CAP) lists[((size_t)2 * NA + dst) * CAP + p2] = e;
            } else {
                int p = atomicAdd(&cnt[3 * NA + src], 1);
                if (p < CAP) lists[((size_t)3 * NA + src) * CAP + p] = e;
            }
        }
        // ---- issue next tile's loads (in flight across the MFMA phases) ----
        if (t + 1 < ET) {
            src = src_n; dst = dst_n;
            const int e1 = eb + (t + 1) * 64 + el;
            const bf16x8* p1 = (const bf16x8*)(x1 + (size_t)src * DN + q * 16);
            const bf16x8* p2 = (const bf16x8*)(x2 + (size_t)dst * DN + q * 16);
            const float4* pe = (const float4*)(ea + (size_t)e1 * DE);
            ra0 = p1[0]; ra1 = p1[1]; rb0 = p2[0]; rb1 = p2[1];
            re0 = pe[q * 2]; re1 = pe[q * 2 + 1];
            if (t + 2 < ET) {
                const int e2 = eb + (t + 2) * 64 + el;
                src_n = ei[e2]; dst_n = ei[NEDGE + e2];
            }
        }
        __syncthreads();

        // ---- layer 1: h[64][64] = feat @ W1 ; wave w owns cols 16w.. ----
        f32x4 acc0 = {0.f,0.f,0.f,0.f}, acc1 = acc0, acc2v = acc0, acc3 = acc0;
#pragma unroll
        for (int kk = 0; kk < 5; kk++) {
            bf16x8 a0 = *(const bf16x8*)&feat[( 0 + m16) * FSTR + kk * 32 + quad * 8];
            bf16x8 a1 = *(const bf16x8*)&feat[(16 + m16) * FSTR + kk * 32 + quad * 8];
            bf16x8 a2 = *(const bf16x8*)&feat[(32 + m16) * FSTR + kk * 32 + quad * 8];
            bf16x8 a3 = *(const bf16x8*)&feat[(48 + m16) * FSTR + kk * 32 + quad * 8];
            acc0 = __builtin_amdgcn_mfma_f32_16x16x32_bf16(a0, b1f[kk], acc0, 0, 0, 0);
            acc1 = __builtin_amdgcn_mfma_f32_16x16x32_bf16(a1, b1f[kk], acc1, 0, 0, 0);
            acc2v = __builtin_amdgcn_mfma_f32_16x16x32_bf16(a2, b1f[kk], acc2v, 0, 0, 0);
            acc3 = __builtin_amdgcn_mfma_f32_16x16x32_bf16(a3, b1f[kk], acc3, 0, 0, 0);
        }
        __syncthreads();                 // all feat reads done before aliasing
        __bf16* hbuf = feat;             // h [64 edges][64], stride HSTR
        {
            f32x4 av[4] = {acc0, acc1, acc2v, acc3};
#pragma unroll
            for (int mt = 0; mt < 4; mt++)
#pragma unroll
                for (int r = 0; r < 4; r++) {
                    float v = av[mt][r] + b1c;
                    v = fmaxf(v, 0.f);
                    hbuf[(mt * 16 + quad * 4 + r) * HSTR + w * 16 + m16] = (__bf16)v;
                }
        }
        __syncthreads();

        // ---- layer 2: o[64][32] = relu(h) @ W2 ----
        f32x4 o0 = {0.f,0.f,0.f,0.f}, o1 = o0;
#pragma unroll
        for (int kk = 0; kk < 2; kk++) {
            bf16x8 a = *(const bf16x8*)&hbuf[(w * 16 + m16) * HSTR + kk * 32 + quad * 8];
            o0 = __builtin_amdgcn_mfma_f32_16x16x32_bf16(a, b2f[0][kk], o0, 0, 0, 0);
            o1 = __builtin_amdgcn_mfma_f32_16x16x32_bf16(a, b2f[1][kk], o1, 0, 0, 0);
        }
        // ---- epilogue: write ne ----
        {
            const size_t row0 = (size_t)k * NEDGE + eb + t * 64;
#pragma unroll
            for (int r = 0; r < 4; r++) {
                const int er = w * 16 + quad * 4 + r;
                ne_out[(row0 + er) * DE + m16]      = o0[r] + b2c0;
                ne_out[(row0 + er) * DE + 16 + m16] = o1[r] + b2c1;
            }
        }
        __syncthreads();                 // h reads done -> next stage may write feat
    }
}

// ---------------- node kernel ----------------
__global__ __launch_bounds__(256, 4) void node_kernel(
    const float* __restrict__ x_a, const float* __restrict__ x_b,
    const float* __restrict__ Wn1, const float* __restrict__ bn1,
    const float* __restrict__ Wn2, const float* __restrict__ bn2,
    float* __restrict__ out,      // nx_a then nx_b, [2*NA][64]
    const float* __restrict__ ne, // [3*NEDGE][32]
    const int* __restrict__ wsi)  // lists ++ cnt
{
    __shared__ __bf16 feat[64 * NSTR];   // concat features [64 nodes][128]

    const int tid = threadIdx.x;
    constexpr int BPT = (NA + 64 * NT2 - 1) / (64 * NT2);  // 391
    const int typ = blockIdx.x / BPT;    // node type (block-uniform)
    const int blk = blockIdx.x % BPT;

    const float* x = typ ? x_b : x_a;
    const float* __restrict__ W1 = Wn1 + (size_t)typ * (DN + 2 * DE) * DH;
    const float* __restrict__ W2 = Wn2 + (size_t)typ * DH * DN;

    const int w = tid >> 6, lane = tid & 63;
    const int m16 = lane & 15, quad = lane >> 4;
    const int q = tid & 3, nl = tid >> 2;

    // ---- weights + biases: once per block ----
    bf16x8 b1f[4];
    {
        const float* wp = W1 + (size_t)(quad * 8) * DH + (w * 16 + m16);
#pragma unroll
        for (int kk = 0; kk < 4; kk++)
#pragma unroll
            for (int j = 0; j < 8; j++)
                b1f[kk][j] = (__bf16)wp[(kk * 32 + j) * DH];
    }
    bf16x8 b2f[4][2];
    {
        const float* wp = W2 + (size_t)(quad * 8) * DN + m16;
#pragma unroll
        for (int nt = 0; nt < 4; nt++)
#pragma unroll
            for (int kk = 0; kk < 2; kk++)
#pragma unroll
                for (int j = 0; j < 8; j++)
                    b2f[nt][kk][j] = (__bf16)wp[(kk * 32 + j) * DN + nt * 16];
    }
    const float b1c = bn1[typ * DH + w * 16 + m16];
    float b2c[4];
#pragma unroll
    for (int nt = 0; nt < 4; nt++) b2c[nt] = bn2[typ * DN + nt * 16 + m16];

    const int* lists = wsi;
    const int* cnt   = wsi + (size_t)4 * NA * CAP;

#pragma unroll 1
    for (int tt = 0; tt < NT2; tt++) {
        const int nb = (blk * NT2 + tt) * 64;
        if (nb >= NA) break;             // block-uniform

        // ---- gather: x | mean1 | mean2 — fused dual-stream predicated loop ----
        {
            const int n = nb + nl;
            const int ng = (n < NA) ? n : NA - 1;
            const int slot1 = (typ ? 2 * NA : 0) + ng;
            const int slot2 = (typ ? 3 * NA : NA) + ng;
            const float* neb1 = ne + (size_t)(typ ? 1 : 0) * NEDGE * DE + q * 8;
            const float* neb2 = ne + (size_t)(typ ? 2 : 1) * NEDGE * DE + q * 8;
            const int deg1 = min(cnt[slot1], CAP);
            const int deg2 = min(cnt[slot2], CAP);
            const int dmax = max(deg1, deg2);
            const int* L1 = lists + (size_t)slot1 * CAP;
            const int* L2 = lists + (size_t)slot2 * CAP;

            f32x4 s1a = {0.f,0.f,0.f,0.f}, s1b = s1a, s2a = s1a, s2b = s1a;
            for (int d = 0; d < dmax; d += 4) {
                i32x4 e4a = *(const i32x4*)&L1[d];
                i32x4 e4b = *(const i32x4*)&L2[d];
#pragma unroll
                for (int i = 0; i < 4; i++) {
                    const bool ok1 = (d + i < deg1);
                    const bool ok2 = (d + i < deg2);
                    const int e1 = ok1 ? e4a[i] : 0;
                    const int e2 = ok2 ? e4b[i] : 0;
                    const f32x4* r1 = (const f32x4*)(neb1 + (size_t)e1 * DE);
                    const f32x4* r2 = (const f32x4*)(neb2 + (size_t)e2 * DE);
                    f32x4 u1 = r1[0], v1 = r1[1];
                    f32x4 u2 = r2[0], v2 = r2[1];
                    if (ok1) { s1a += u1; s1b += v1; }
                    if (ok2) { s2a += u2; s2b += v2; }
                }
            }
            const float inv1 = 1.0f / fmaxf((float)deg1, 1.0f);
            const float inv2 = 1.0f / fmaxf((float)deg2, 1.0f);
            s1a *= inv1; s1b *= inv1; s2a *= inv2; s2b *= inv2;

            const float4* px = (const float4*)(x + (size_t)ng * DN);
#pragma unroll
            for (int i = 0; i < 4; i++) {
                float4 v = px[q * 4 + i];
                bf16x4 t4 = {(__bf16)v.x, (__bf16)v.y, (__bf16)v.z, (__bf16)v.w};
                *(bf16x4*)&feat[nl * NSTR + q * 16 + i * 4] = t4;
            }
            bf16x4 m1a = {(__bf16)s1a[0], (__bf16)s1a[1], (__bf16)s1a[2], (__bf16)s1a[3]};
            bf16x4 m1b = {(__bf16)s1b[0], (__bf16)s1b[1], (__bf16)s1b[2], (__bf16)s1b[3]};
            bf16x4 m2a = {(__bf16)s2a[0], (__bf16)s2a[1], (__bf16)s2a[2], (__bf16)s2a[3]};
            bf16x4 m2b = {(__bf16)s2b[0], (__bf16)s2b[1], (__bf16)s2b[2], (__bf16)s2b[3]};
            *(bf16x4*)&feat[nl * NSTR + 64 + q * 8 + 0] = m1a;
            *(bf16x4*)&feat[nl * NSTR + 64 + q * 8 + 4] = m1b;
            *(bf16x4*)&feat[nl * NSTR + 96 + q * 8 + 0] = m2a;
            *(bf16x4*)&feat[nl * NSTR + 96 + q * 8 + 4] = m2b;
        }
        __syncthreads();

        // ---- layer 1: h = feat[64][128] @ Wn1 ----
        f32x4 acc0 = {0.f,0.f,0.f,0.f}, acc1 = acc0, acc2v = acc0, acc3 = acc0;
#pragma unroll
        for (int kk = 0; kk < 4; kk++) {
            bf16x8 a0 = *(const bf16x8*)&feat[( 0 + m16) * NSTR + kk * 32 + quad * 8];
            bf16x8 a1 = *(const bf16x8*)&feat[(16 + m16) * NSTR + kk * 32 + quad * 8];
            bf16x8 a2 = *(const bf16x8*)&feat[(32 + m16) * NSTR + kk * 32 + quad * 8];
            bf16x8 a3 = *(const bf16x8*)&feat[(48 + m16) * NSTR + kk * 32 + quad * 8];
            acc0 = __builtin_amdgcn_mfma_f32_16x16x32_bf16(a0, b1f[kk], acc0, 0, 0, 0);
            acc1 = __builtin_amdgcn_mfma_f32_16x16x32_bf16(a1, b1f[kk], acc1, 0, 0, 0);
            acc2v = __builtin_amdgcn_mfma_f32_16x16x32_bf16(a2, b1f[kk], acc2v, 0, 0, 0);
            acc3 = __builtin_amdgcn_mfma_f32_16x16x32_bf16(a3, b1f[kk], acc3, 0, 0, 0);
        }
        __syncthreads();
        __bf16* hbuf = feat;             // alias, h [64 nodes][64], stride HSTR
        {
            f32x4 av[4] = {acc0, acc1, acc2v, acc3};
#pragma unroll
            for (int mt = 0; mt < 4; mt++)
#pragma unroll
                for (int r = 0; r < 4; r++) {
                    float v = av[mt][r] + b1c;
                    v = fmaxf(v, 0.f);
                    hbuf[(mt * 16 + quad * 4 + r) * HSTR + w * 16 + m16] = (__bf16)v;
                }
        }
        __syncthreads();

        // ---- layer 2: nx[64][64] = relu(h) @ Wn2 ----
        f32x4 o0 = {0.f,0.f,0.f,0.f}, o1 = o0, o2 = o0, o3 = o0;
#pragma unroll
        for (int kk = 0; kk < 2; kk++) {
            bf16x8 a = *(const bf16x8*)&hbuf[(w * 16 + m16) * HSTR + kk * 32 + quad * 8];
            o0 = __builtin_amdgcn_mfma_f32_16x16x32_bf16(a, b2f[0][kk], o0, 0, 0, 0);
            o1 = __builtin_amdgcn_mfma_f32_16x16x32_bf16(a, b2f[1][kk], o1, 0, 0, 0);
            o2 = __builtin_amdgcn_mfma_f32_16x16x32_bf16(a, b2f[2][kk], o2, 0, 0, 0);
            o3 = __builtin_amdgcn_mfma_f32_16x16x32_bf16(a, b2f[3][kk], o3, 0, 0, 0);
        }
#pragma unroll
        for (int nt = 0; nt < 4; nt++) {
            const int col = nt * 16 + m16;
            const f32x4 oo = (nt == 0) ? o0 : (nt == 1) ? o1 : (nt == 2) ? o2 : o3;
#pragma unroll
            for (int r = 0; r < 4; r++) {
                const int n = nb + w * 16 + quad * 4 + r;
                if (n < NA)
                    out[((size_t)typ * NA + n) * DN + col] = oo[r] + b2c[nt];
            }
        }
        __syncthreads();                 // h reads done -> next tile stage
    }
}

extern "C" void kernel_launch(void* const* d_in, const int* in_sizes, int n_in,
                              void* d_out, int out_size, void* d_ws, size_t ws_size,
                              hipStream_t stream)
{
    const float* x_a  = (const float*)d_in[0];
    const float* x_b  = (const float*)d_in[1];
    const int*   ei_aa = (const int*)d_in[2];
    const int*   ei_ab = (const int*)d_in[3];
    const int*   ei_bb = (const int*)d_in[4];
    const float* ea_aa = (const float*)d_in[5];
    const float* ea_ab = (const float*)d_in[6];
    const float* ea_bb = (const float*)d_in[7];
    const float* We1 = (const float*)d_in[8];
    const float* be1 = (const float*)d_in[9];
    const float* We2 = (const float*)d_in[10];
    const float* be2 = (const float*)d_in[11];
    const float* Wn1 = (const float*)d_in[12];
    const float* bn1 = (const float*)d_in[13];
    const float* Wn2 = (const float*)d_in[14];
    const float* bn2 = (const float*)d_in[15];

    float* out = (float*)d_out;
    int*   wsi = (int*)d_ws;

    // bf16 x copy lives in out's nx region (25.6 MB < 51.2 MB); edge kernel
    // reads it, node kernel overwrites it with the final nx.
    __bf16* xab = (__bf16*)out;
    int* cnt = wsi + (size_t)4 * NA * CAP;

    prep_kernel<<<2048, 256, 0, stream>>>((const float4*)x_a, (const float4*)x_b,
                                          xab, cnt);

    constexpr int BPT_E = NEDGE / (64 * ET);     // 625
    edge_kernel<<<3 * BPT_E, 256, 0, stream>>>(
        xab, ei_aa, ei_ab, ei_bb, ea_aa, ea_ab, ea_bb,
        We1, be1, We2, be2, out + (size_t)2 * NA * DN, wsi);

    constexpr int BPT_N = (NA + 64 * NT2 - 1) / (64 * NT2);  // 391
    node_kernel<<<2 * BPT_N, 256, 0, stream>>>(
        x_a, x_b, Wn1, bn1, Wn2, bn2, out, out + (size_t)2 * NA * DN, wsi);
}